// Round 7
// baseline (141.264 us; speedup 1.0000x reference)
//
#include <hip/hip_runtime.h>
#include <stdint.h>

// HashedInterpolator R6: R5 + second-level in-bucket sort to 4^3-cell regions
// (Morton order). A region's 5^3=125 corner lines (~8KB) fit L1, so K4's
// gathers go from 16.8M L2 requests to ~4M (L1 serves the rest).
// Pipeline: K1 hist64 -> K2 scan64 -> K3 coalesced bucket scatter ->
// K3b in-bucket counting sort (512 fine bins, writes confined to the bucket's
// 512KB L2-resident window) -> K4 interp + direct scatter to out[orig].

#define HASH_MASK 0x3FFFFFu
#define P1 19349663u
#define P2 83492791u
#define NBUCK 64
#define FBINS 512                 // 8^3 regions per bucket (region = 4^3 cells)
#define PPT 16                    // points per thread in K1/K3
#define K3_BLOCK 256
#define PPB (K3_BLOCK * PPT)      // 4096 points per block

__device__ __forceinline__ uint32_t bucket_of(float px, float py, float pz) {
    uint32_t bx = ((uint32_t)(int)floorf(px * 128.0f)) >> 5;  // 0..3
    uint32_t by = ((uint32_t)(int)floorf(py * 128.0f)) >> 5;
    uint32_t bz = ((uint32_t)(int)floorf(pz * 128.0f)) >> 5;
    return (bx << 4) | (by << 2) | bz;
}

__device__ __forceinline__ uint32_t spread3(uint32_t v) {
    // 3-bit value -> bits 0,3,6
    return (v & 1u) | ((v & 2u) << 2) | ((v & 4u) << 4);
}

// fine bin within bucket: region coord = (cell>>2) & 7 per axis, Morton-coded
__device__ __forceinline__ uint32_t fine_bin(float px, float py, float pz) {
    uint32_t cx = (((uint32_t)(int)floorf(px * 128.0f)) >> 2) & 7u;
    uint32_t cy = (((uint32_t)(int)floorf(py * 128.0f)) >> 2) & 7u;
    uint32_t cz = (((uint32_t)(int)floorf(pz * 128.0f)) >> 2) & 7u;
    return (spread3(cx) << 2) | (spread3(cy) << 1) | spread3(cz);
}

__device__ __forceinline__ float4 interp_point(float px, float py, float pz,
                                               const float* __restrict__ table) {
    int lx = (int)floorf(px * 128.0f);
    int ly = (int)floorf(py * 128.0f);
    int lz = (int)floorf(pz * 128.0f);

    const float inv = 1.0f / 128.0f;  // exact
    float w0x = (px - (float)lx * inv) * 128.0f;
    float w1x = ((float)(lx + 1) * inv - px) * 128.0f;
    float w0y = (py - (float)ly * inv) * 128.0f;
    float w1y = ((float)(ly + 1) * inv - py) * 128.0f;
    float w0z = (pz - (float)lz * inv) * 128.0f;
    float w1z = ((float)(lz + 1) * inv - pz) * 128.0f;

    uint32_t hx0 = (uint32_t)lx;
    uint32_t hx1 = (uint32_t)(lx + 1);
    uint32_t hy0 = (uint32_t)ly * P1;
    uint32_t hy1 = (uint32_t)(ly + 1) * P1;
    uint32_t hz0 = (uint32_t)lz * P2;
    uint32_t hz1 = (uint32_t)(lz + 1) * P2;

    float acc0 = 0.f, acc1 = 0.f, acc2 = 0.f, acc3 = 0.f;
#pragma unroll
    for (int c = 0; c < 8; ++c) {
        int bx = (c >> 2) & 1;
        int by = (c >> 1) & 1;
        int bz = c & 1;
        uint32_t h = ((bx ? hx1 : hx0) ^ (by ? hy1 : hy0) ^ (bz ? hz1 : hz0)) & HASH_MASK;
        const float4 v = *reinterpret_cast<const float4*>(table + (size_t)h * 4);
        float w = ((bx ? w1x : w0x) * (by ? w1y : w0y)) * (bz ? w1z : w0z);
        acc0 += v.x * w;
        acc1 += v.y * w;
        acc2 += v.z * w;
        acc3 += v.w * w;
    }
    return make_float4(acc0, acc1, acc2, acc3);
}

// ---- K1: per-block LDS histogram -> 64 global atomics per block ----
__global__ __launch_bounds__(K3_BLOCK) void hist_kernel(
    const float* __restrict__ pos, uint32_t* __restrict__ hist, int batch)
{
    __shared__ uint32_t h[NBUCK];
    int tid = threadIdx.x;
    size_t start = (size_t)blockIdx.x * PPB;
    if (tid < NBUCK) h[tid] = 0;
    __syncthreads();
#pragma unroll
    for (int k = 0; k < PPT; ++k) {
        size_t i = start + (size_t)k * K3_BLOCK + tid;
        if (i < (size_t)batch) {
            float px = pos[3 * i + 0];
            float py = pos[3 * i + 1];
            float pz = pos[3 * i + 2];
            atomicAdd(&h[bucket_of(px, py, pz)], 1u);
        }
    }
    __syncthreads();
    if (tid < NBUCK && h[tid]) atomicAdd(&hist[tid], h[tid]);
}

// ---- K2: 64-bin exclusive scan (one wave) ----
__global__ __launch_bounds__(64) void scan_kernel(
    const uint32_t* __restrict__ hist, uint32_t* __restrict__ cursor)
{
    int t = threadIdx.x;
    uint32_t v = hist[t];
    uint32_t inc = v;
    for (int off = 1; off < 64; off <<= 1) {
        uint32_t n = __shfl_up(inc, off);
        if (t >= off) inc += n;
    }
    cursor[t] = inc - v;   // exclusive
}

// ---- K3: LDS-staged scatter, coalesced global writes ----
// After this kernel cursor[b] == end offset of bucket b (inclusive-scan).
__global__ __launch_bounds__(K3_BLOCK) void scatter_kernel(
    const float* __restrict__ pos, uint32_t* __restrict__ cursor,
    float4* __restrict__ sorted, int batch)
{
    __shared__ float4 staged[PPB];          // 64 KB
    __shared__ uint32_t h[NBUCK], lbase[NBUCK], gbase[NBUCK], lcur[NBUCK];
    int tid = threadIdx.x;
    size_t start = (size_t)blockIdx.x * PPB;

    if (tid < NBUCK) h[tid] = 0;
    __syncthreads();

    float px[PPT], py[PPT], pz[PPT];
    uint32_t bb[PPT];
#pragma unroll
    for (int k = 0; k < PPT; ++k) {
        size_t i = start + (size_t)k * K3_BLOCK + tid;
        px[k] = pos[3 * i + 0];
        py[k] = pos[3 * i + 1];
        pz[k] = pos[3 * i + 2];
        bb[k] = bucket_of(px[k], py[k], pz[k]);
        atomicAdd(&h[bb[k]], 1u);
    }
    __syncthreads();

    if (tid < NBUCK) {
        uint32_t v = h[tid];
        uint32_t inc = v;
        for (int off = 1; off < 64; off <<= 1) {
            uint32_t n = __shfl_up(inc, off);
            if (tid >= off) inc += n;
        }
        uint32_t excl = inc - v;
        lbase[tid] = excl;
        lcur[tid] = excl;
        gbase[tid] = atomicAdd(&cursor[tid], v);
    }
    __syncthreads();

#pragma unroll
    for (int k = 0; k < PPT; ++k) {
        size_t i = start + (size_t)k * K3_BLOCK + tid;
        uint32_t slot = atomicAdd(&lcur[bb[k]], 1u);
        staged[slot] = make_float4(px[k], py[k], pz[k], __uint_as_float((uint32_t)i));
    }
    __syncthreads();

#pragma unroll
    for (int k = 0; k < PPT; ++k) {
        int j = k * K3_BLOCK + tid;
        float4 s = staged[j];
        uint32_t b = bucket_of(s.x, s.y, s.z);
        sorted[gbase[b] + ((uint32_t)j - lbase[b])] = s;
    }
}

// ---- K3b: in-bucket counting sort into 512 Morton fine regions ----
// One fat block per bucket. Writes are scattered but confined to the bucket's
// ~512KB window (L2-resident).
__global__ __launch_bounds__(1024) void subsort_kernel(
    const float4* __restrict__ sorted, const uint32_t* __restrict__ cursor,
    float4* __restrict__ sorted2)
{
    __shared__ uint32_t hist[FBINS];   // then running cursor
    __shared__ uint32_t scanb[FBINS];
    int b = blockIdx.x;
    int tid = threadIdx.x;
    uint32_t start = (b == 0) ? 0u : cursor[b - 1];
    uint32_t end = cursor[b];
    uint32_t n = end - start;

    if (tid < FBINS) hist[tid] = 0;
    __syncthreads();

    // pass A: fine-bin histogram
    for (uint32_t j = tid; j < n; j += 1024) {
        float4 s = sorted[start + j];
        atomicAdd(&hist[fine_bin(s.x, s.y, s.z)], 1u);
    }
    __syncthreads();

    // Hillis-Steele inclusive scan over 512 bins
    uint32_t v = (tid < FBINS) ? hist[tid] : 0u;
    if (tid < FBINS) scanb[tid] = v;
    __syncthreads();
    for (int off = 1; off < FBINS; off <<= 1) {
        uint32_t add = 0;
        if (tid < FBINS && tid >= off) add = scanb[tid - off];
        __syncthreads();
        if (tid < FBINS) scanb[tid] += add;
        __syncthreads();
    }
    if (tid < FBINS) hist[tid] = scanb[tid] - v;   // exclusive base -> cursor
    __syncthreads();

    // pass B: scatter within window
    for (uint32_t j = tid; j < n; j += 1024) {
        float4 s = sorted[start + j];
        uint32_t slot = atomicAdd(&hist[fine_bin(s.x, s.y, s.z)], 1u);
        sorted2[start + slot] = s;
    }
}

// ---- K4: interpolate sorted points, scatter result to out[orig] ----
__global__ __launch_bounds__(256) void interp_scatter_kernel(
    const float4* __restrict__ sorted, const float* __restrict__ table,
    float4* __restrict__ out4, int batch, int nwg)
{
    int bid = blockIdx.x;
    int q = nwg >> 3;
    int swz = (bid & 7) * q + (bid >> 3);
    int i = swz * 256 + threadIdx.x;
    if (i >= batch) return;

    float4 s = sorted[i];
    float4 r = interp_point(s.x, s.y, s.z, table);
    uint32_t orig = __float_as_uint(s.w);
    out4[orig] = r;
}

// ---- fallback: direct (R0) ----
__global__ __launch_bounds__(256) void interp_direct_kernel(
    const float* __restrict__ pos, const float* __restrict__ table,
    float4* __restrict__ out4, int batch)
{
    int i = blockIdx.x * 256 + threadIdx.x;
    if (i >= batch) return;
    float px = pos[3 * (size_t)i + 0];
    float py = pos[3 * (size_t)i + 1];
    float pz = pos[3 * (size_t)i + 2];
    out4[i] = interp_point(px, py, pz, table);
}

extern "C" void kernel_launch(void* const* d_in, const int* in_sizes, int n_in,
                              void* d_out, int out_size, void* d_ws, size_t ws_size,
                              hipStream_t stream) {
    const float* pos   = (const float*)d_in[0];   // (2^21, 3)
    const float* table = (const float*)d_in[1];   // (2^22, 4)
    float4* out4 = (float4*)d_out;                // (2^21, 4)

    int batch = in_sizes[0] / 3;                  // 2^21
    int blocks256 = (batch + 255) / 256;          // 8192

    size_t sorted_off  = 512;
    size_t sorted2_off = sorted_off + (size_t)batch * 16;
    size_t need1 = sorted_off + (size_t)batch * 16;
    size_t need2 = sorted2_off + (size_t)batch * 16;

    bool exact = (batch % PPB == 0) && ((blocks256 & 7) == 0);
    if (ws_size < need1 || !exact) {
        interp_direct_kernel<<<blocks256, 256, 0, stream>>>(pos, table, out4, batch);
        return;
    }

    uint32_t* hist    = (uint32_t*)d_ws;                         // 256 B
    uint32_t* cursor  = (uint32_t*)((char*)d_ws + 256);          // 256 B
    float4*   sorted  = (float4*)((char*)d_ws + sorted_off);     // 32 MB
    float4*   sorted2 = (float4*)((char*)d_ws + sorted2_off);    // 32 MB

    int sblocks = batch / PPB;                                   // 512

    hipMemsetAsync(hist, 0, NBUCK * sizeof(uint32_t), stream);
    hist_kernel<<<sblocks, K3_BLOCK, 0, stream>>>(pos, hist, batch);
    scan_kernel<<<1, 64, 0, stream>>>(hist, cursor);
    scatter_kernel<<<sblocks, K3_BLOCK, 0, stream>>>(pos, cursor, sorted, batch);

    if (ws_size >= need2) {
        subsort_kernel<<<NBUCK, 1024, 0, stream>>>(sorted, cursor, sorted2);
        interp_scatter_kernel<<<blocks256, 256, 0, stream>>>(sorted2, table, out4, batch, blocks256);
    } else {
        interp_scatter_kernel<<<blocks256, 256, 0, stream>>>(sorted, table, out4, batch, blocks256);
    }
}

// Round 8
// 138.846 us; speedup vs baseline: 1.0174x; 1.0174x over previous
//
#include <hip/hip_runtime.h>
#include <stdint.h>

// HashedInterpolator R7: R6 + wave-per-region LDS corner staging in K4.
// A 4^3-cell region has 5^3=125 corners. One wave per region: gather the 125
// table rows ONCE into LDS (2KB), then the region's ~64 points interpolate
// from LDS. Global gather requests: 16.8M -> 32768*125 = 4.1M.
// Subsort additionally exports fstart[32768] (global fine-region offsets).

#define HASH_MASK 0x3FFFFFu
#define P1 19349663u
#define P2 83492791u
#define NBUCK 64
#define FBINS 512                 // 8^3 regions per bucket (region = 4^3 cells)
#define NREG (NBUCK * FBINS)      // 32768 regions
#define PPT 16
#define K3_BLOCK 256
#define PPB (K3_BLOCK * PPT)      // 4096 points per block

__device__ __forceinline__ uint32_t bucket_of(float px, float py, float pz) {
    uint32_t bx = ((uint32_t)(int)floorf(px * 128.0f)) >> 5;
    uint32_t by = ((uint32_t)(int)floorf(py * 128.0f)) >> 5;
    uint32_t bz = ((uint32_t)(int)floorf(pz * 128.0f)) >> 5;
    return (bx << 4) | (by << 2) | bz;
}

__device__ __forceinline__ uint32_t spread3(uint32_t v) {
    return (v & 1u) | ((v & 2u) << 2) | ((v & 4u) << 4);
}

__device__ __forceinline__ uint32_t fine_bin(float px, float py, float pz) {
    uint32_t cx = (((uint32_t)(int)floorf(px * 128.0f)) >> 2) & 7u;
    uint32_t cy = (((uint32_t)(int)floorf(py * 128.0f)) >> 2) & 7u;
    uint32_t cz = (((uint32_t)(int)floorf(pz * 128.0f)) >> 2) & 7u;
    return (spread3(cx) << 2) | (spread3(cy) << 1) | spread3(cz);
}

__device__ __forceinline__ float4 interp_point(float px, float py, float pz,
                                               const float* __restrict__ table) {
    int lx = (int)floorf(px * 128.0f);
    int ly = (int)floorf(py * 128.0f);
    int lz = (int)floorf(pz * 128.0f);
    const float inv = 1.0f / 128.0f;
    float w0x = (px - (float)lx * inv) * 128.0f;
    float w1x = ((float)(lx + 1) * inv - px) * 128.0f;
    float w0y = (py - (float)ly * inv) * 128.0f;
    float w1y = ((float)(ly + 1) * inv - py) * 128.0f;
    float w0z = (pz - (float)lz * inv) * 128.0f;
    float w1z = ((float)(lz + 1) * inv - pz) * 128.0f;
    uint32_t hx0 = (uint32_t)lx, hx1 = (uint32_t)(lx + 1);
    uint32_t hy0 = (uint32_t)ly * P1, hy1 = (uint32_t)(ly + 1) * P1;
    uint32_t hz0 = (uint32_t)lz * P2, hz1 = (uint32_t)(lz + 1) * P2;
    float acc0 = 0.f, acc1 = 0.f, acc2 = 0.f, acc3 = 0.f;
#pragma unroll
    for (int c = 0; c < 8; ++c) {
        int bx = (c >> 2) & 1, by = (c >> 1) & 1, bz = c & 1;
        uint32_t h = ((bx ? hx1 : hx0) ^ (by ? hy1 : hy0) ^ (bz ? hz1 : hz0)) & HASH_MASK;
        const float4 v = *reinterpret_cast<const float4*>(table + (size_t)h * 4);
        float w = ((bx ? w1x : w0x) * (by ? w1y : w0y)) * (bz ? w1z : w0z);
        acc0 += v.x * w; acc1 += v.y * w; acc2 += v.z * w; acc3 += v.w * w;
    }
    return make_float4(acc0, acc1, acc2, acc3);
}

// ---- K1: per-block LDS histogram ----
__global__ __launch_bounds__(K3_BLOCK) void hist_kernel(
    const float* __restrict__ pos, uint32_t* __restrict__ hist, int batch)
{
    __shared__ uint32_t h[NBUCK];
    int tid = threadIdx.x;
    size_t start = (size_t)blockIdx.x * PPB;
    if (tid < NBUCK) h[tid] = 0;
    __syncthreads();
#pragma unroll
    for (int k = 0; k < PPT; ++k) {
        size_t i = start + (size_t)k * K3_BLOCK + tid;
        if (i < (size_t)batch) {
            float px = pos[3 * i + 0];
            float py = pos[3 * i + 1];
            float pz = pos[3 * i + 2];
            atomicAdd(&h[bucket_of(px, py, pz)], 1u);
        }
    }
    __syncthreads();
    if (tid < NBUCK && h[tid]) atomicAdd(&hist[tid], h[tid]);
}

// ---- K2: 64-bin exclusive scan ----
__global__ __launch_bounds__(64) void scan_kernel(
    const uint32_t* __restrict__ hist, uint32_t* __restrict__ cursor)
{
    int t = threadIdx.x;
    uint32_t v = hist[t];
    uint32_t inc = v;
    for (int off = 1; off < 64; off <<= 1) {
        uint32_t n = __shfl_up(inc, off);
        if (t >= off) inc += n;
    }
    cursor[t] = inc - v;
}

// ---- K3: LDS-staged coarse scatter (coalesced) ----
// After this kernel cursor[b] == inclusive end offset of bucket b.
__global__ __launch_bounds__(K3_BLOCK) void scatter_kernel(
    const float* __restrict__ pos, uint32_t* __restrict__ cursor,
    float4* __restrict__ sorted, int batch)
{
    __shared__ float4 staged[PPB];
    __shared__ uint32_t h[NBUCK], lbase[NBUCK], gbase[NBUCK], lcur[NBUCK];
    int tid = threadIdx.x;
    size_t start = (size_t)blockIdx.x * PPB;

    if (tid < NBUCK) h[tid] = 0;
    __syncthreads();

    float px[PPT], py[PPT], pz[PPT];
    uint32_t bb[PPT];
#pragma unroll
    for (int k = 0; k < PPT; ++k) {
        size_t i = start + (size_t)k * K3_BLOCK + tid;
        px[k] = pos[3 * i + 0];
        py[k] = pos[3 * i + 1];
        pz[k] = pos[3 * i + 2];
        bb[k] = bucket_of(px[k], py[k], pz[k]);
        atomicAdd(&h[bb[k]], 1u);
    }
    __syncthreads();

    if (tid < NBUCK) {
        uint32_t v = h[tid];
        uint32_t inc = v;
        for (int off = 1; off < 64; off <<= 1) {
            uint32_t n = __shfl_up(inc, off);
            if (tid >= off) inc += n;
        }
        uint32_t excl = inc - v;
        lbase[tid] = excl;
        lcur[tid] = excl;
        gbase[tid] = atomicAdd(&cursor[tid], v);
    }
    __syncthreads();

#pragma unroll
    for (int k = 0; k < PPT; ++k) {
        size_t i = start + (size_t)k * K3_BLOCK + tid;
        uint32_t slot = atomicAdd(&lcur[bb[k]], 1u);
        staged[slot] = make_float4(px[k], py[k], pz[k], __uint_as_float((uint32_t)i));
    }
    __syncthreads();

#pragma unroll
    for (int k = 0; k < PPT; ++k) {
        int j = k * K3_BLOCK + tid;
        float4 s = staged[j];
        uint32_t b = bucket_of(s.x, s.y, s.z);
        sorted[gbase[b] + ((uint32_t)j - lbase[b])] = s;
    }
}

// ---- K3b: in-bucket counting sort; exports global fine-region bases ----
__global__ __launch_bounds__(1024) void subsort_kernel(
    const float4* __restrict__ sorted, const uint32_t* __restrict__ cursor,
    float4* __restrict__ sorted2, uint32_t* __restrict__ fstart)
{
    __shared__ uint32_t hist[FBINS];
    __shared__ uint32_t scanb[FBINS];
    int b = blockIdx.x;
    int tid = threadIdx.x;
    uint32_t start = (b == 0) ? 0u : cursor[b - 1];
    uint32_t end = cursor[b];
    uint32_t n = end - start;

    if (tid < FBINS) hist[tid] = 0;
    __syncthreads();

    for (uint32_t j = tid; j < n; j += 1024) {
        float4 s = sorted[start + j];
        atomicAdd(&hist[fine_bin(s.x, s.y, s.z)], 1u);
    }
    __syncthreads();

    uint32_t v = (tid < FBINS) ? hist[tid] : 0u;
    if (tid < FBINS) scanb[tid] = v;
    __syncthreads();
    for (int off = 1; off < FBINS; off <<= 1) {
        uint32_t add = 0;
        if (tid < FBINS && tid >= off) add = scanb[tid - off];
        __syncthreads();
        if (tid < FBINS) scanb[tid] += add;
        __syncthreads();
    }
    if (tid < FBINS) {
        uint32_t excl = scanb[tid] - v;
        hist[tid] = excl;                       // running cursor for pass B
        fstart[b * FBINS + tid] = start + excl; // global region base
    }
    __syncthreads();

    for (uint32_t j = tid; j < n; j += 1024) {
        float4 s = sorted[start + j];
        uint32_t slot = atomicAdd(&hist[fine_bin(s.x, s.y, s.z)], 1u);
        sorted2[start + slot] = s;
    }
}

// ---- K4: wave-per-region, LDS-staged corners, scatter to out[orig] ----
__global__ __launch_bounds__(256) void interp_region_kernel(
    const float4* __restrict__ sorted2, const uint32_t* __restrict__ fstart,
    const float* __restrict__ table, float4* __restrict__ out4,
    int batch, int nwg)
{
    __shared__ float4 corners[4][125];   // 8 KB, one slab per wave
    int bid = blockIdx.x;
    int q = nwg >> 3;                    // nwg divisible by 8
    int swz = (bid & 7) * q + (bid >> 3);
    int wave = threadIdx.x >> 6;
    int lane = threadIdx.x & 63;
    uint32_t r = (uint32_t)swz * 4 + wave;          // region id 0..32767
    uint32_t start = fstart[r];
    uint32_t end = (r == NREG - 1) ? (uint32_t)batch : fstart[r + 1];
    if (start >= end) return;            // empty region; no __syncthreads below

    // region base cell from first point (all points in span share the region)
    float4 s0 = sorted2[start];
    int rbx = (((int)floorf(s0.x * 128.0f)) >> 2) << 2;
    int rby = (((int)floorf(s0.y * 128.0f)) >> 2) << 2;
    int rbz = (((int)floorf(s0.z * 128.0f)) >> 2) << 2;

    // stage 125 corner rows (each lane 2 iters)
    for (int idx = lane; idx < 125; idx += 64) {
        int ci = idx / 25;
        int rem = idx - ci * 25;
        int cj = rem / 5;
        int ck = rem - cj * 5;
        uint32_t h = ((uint32_t)(rbx + ci) ^
                      (uint32_t)(rby + cj) * P1 ^
                      (uint32_t)(rbz + ck) * P2) & HASH_MASK;
        corners[wave][idx] = *reinterpret_cast<const float4*>(table + (size_t)h * 4);
    }
    // intra-wave LDS write -> read fence (lockstep wave; no cross-wave sharing)
    asm volatile("s_waitcnt lgkmcnt(0)" ::: "memory");

    const float inv = 1.0f / 128.0f;
    for (uint32_t p = start + lane; p < end; p += 64) {
        float4 s = sorted2[p];
        float px = s.x, py = s.y, pz = s.z;
        int lx = (int)floorf(px * 128.0f);
        int ly = (int)floorf(py * 128.0f);
        int lz = (int)floorf(pz * 128.0f);
        float w0x = (px - (float)lx * inv) * 128.0f;
        float w1x = ((float)(lx + 1) * inv - px) * 128.0f;
        float w0y = (py - (float)ly * inv) * 128.0f;
        float w1y = ((float)(ly + 1) * inv - py) * 128.0f;
        float w0z = (pz - (float)lz * inv) * 128.0f;
        float w1z = ((float)(lz + 1) * inv - pz) * 128.0f;
        int li = lx - rbx, lj = ly - rby, lk = lz - rbz;   // in [0,3]
        int base = li * 25 + lj * 5 + lk;

        float acc0 = 0.f, acc1 = 0.f, acc2 = 0.f, acc3 = 0.f;
#pragma unroll
        for (int c = 0; c < 8; ++c) {
            int bx = (c >> 2) & 1, by = (c >> 1) & 1, bz = c & 1;
            float4 v = corners[wave][base + bx * 25 + by * 5 + bz];
            float w = ((bx ? w1x : w0x) * (by ? w1y : w0y)) * (bz ? w1z : w0z);
            acc0 += v.x * w; acc1 += v.y * w; acc2 += v.z * w; acc3 += v.w * w;
        }
        out4[__float_as_uint(s.w)] = make_float4(acc0, acc1, acc2, acc3);
    }
}

// ---- K4 alt (R5 path): interp sorted, scatter to out[orig] ----
__global__ __launch_bounds__(256) void interp_scatter_kernel(
    const float4* __restrict__ sorted, const float* __restrict__ table,
    float4* __restrict__ out4, int batch, int nwg)
{
    int bid = blockIdx.x;
    int q = nwg >> 3;
    int swz = (bid & 7) * q + (bid >> 3);
    int i = swz * 256 + threadIdx.x;
    if (i >= batch) return;
    float4 s = sorted[i];
    float4 r = interp_point(s.x, s.y, s.z, table);
    out4[__float_as_uint(s.w)] = r;
}

// ---- fallback: direct ----
__global__ __launch_bounds__(256) void interp_direct_kernel(
    const float* __restrict__ pos, const float* __restrict__ table,
    float4* __restrict__ out4, int batch)
{
    int i = blockIdx.x * 256 + threadIdx.x;
    if (i >= batch) return;
    out4[i] = interp_point(pos[3 * (size_t)i], pos[3 * (size_t)i + 1],
                           pos[3 * (size_t)i + 2], table);
}

extern "C" void kernel_launch(void* const* d_in, const int* in_sizes, int n_in,
                              void* d_out, int out_size, void* d_ws, size_t ws_size,
                              hipStream_t stream) {
    const float* pos   = (const float*)d_in[0];   // (2^21, 3)
    const float* table = (const float*)d_in[1];   // (2^22, 4)
    float4* out4 = (float4*)d_out;                // (2^21, 4)

    int batch = in_sizes[0] / 3;                  // 2^21
    int blocks256 = (batch + 255) / 256;          // 8192

    size_t sorted_off  = 512;
    size_t sorted2_off = sorted_off + (size_t)batch * 16;
    size_t fstart_off  = sorted2_off + (size_t)batch * 16;
    size_t need1 = sorted_off + (size_t)batch * 16;
    size_t need2 = sorted2_off + (size_t)batch * 16;
    size_t need3 = fstart_off + (size_t)NREG * 4;

    int rblocks = NREG / 4;                       // 8192 region blocks

    bool exact = (batch % PPB == 0) && ((blocks256 & 7) == 0) && ((rblocks & 7) == 0);
    if (ws_size < need1 || !exact) {
        interp_direct_kernel<<<blocks256, 256, 0, stream>>>(pos, table, out4, batch);
        return;
    }

    uint32_t* hist    = (uint32_t*)d_ws;
    uint32_t* cursor  = (uint32_t*)((char*)d_ws + 256);
    float4*   sorted  = (float4*)((char*)d_ws + sorted_off);
    float4*   sorted2 = (float4*)((char*)d_ws + sorted2_off);
    uint32_t* fstart  = (uint32_t*)((char*)d_ws + fstart_off);

    int sblocks = batch / PPB;                    // 512

    hipMemsetAsync(hist, 0, NBUCK * sizeof(uint32_t), stream);
    hist_kernel<<<sblocks, K3_BLOCK, 0, stream>>>(pos, hist, batch);
    scan_kernel<<<1, 64, 0, stream>>>(hist, cursor);
    scatter_kernel<<<sblocks, K3_BLOCK, 0, stream>>>(pos, cursor, sorted, batch);

    if (ws_size >= need3) {
        subsort_kernel<<<NBUCK, 1024, 0, stream>>>(sorted, cursor, sorted2, fstart);
        interp_region_kernel<<<rblocks, 256, 0, stream>>>(sorted2, fstart, table, out4,
                                                          batch, rblocks);
    } else if (ws_size >= need2) {
        subsort_kernel<<<NBUCK, 1024, 0, stream>>>(sorted, cursor, sorted2, fstart);
        interp_scatter_kernel<<<blocks256, 256, 0, stream>>>(sorted2, table, out4,
                                                             batch, blocks256);
    } else {
        interp_scatter_kernel<<<blocks256, 256, 0, stream>>>(sorted, table, out4,
                                                             batch, blocks256);
    }
}

// Round 9
// 110.885 us; speedup vs baseline: 1.2740x; 1.2522x over previous
//
#include <hip/hip_runtime.h>
#include <stdint.h>

// HashedInterpolator R8: superregion granularity 8^3 cells (4096 superregions).
// Pipeline:
//   K1 hist64 -> K2 scan64 -> K3 coalesced bucket scatter (64 buckets of 32^3)
//   -> fineA/B/C: parallel in-bucket counting sort to 64 fine bins (= 8^3
//      superregions), 1024 blocks, coalesced writes, no global atomics
//   -> K4 block-per-superregion: stage 9^3=729 corners in LDS (11.7KB, shared
//      by whole block), interpolate ~512 points, scatter to out[orig].
// Corner staging requests: 32768*125 (R7) -> 4096*729 = 3.0M.

#define HASH_MASK 0x3FFFFFu
#define P1 19349663u
#define P2 83492791u
#define NBUCK 64
#define CHUNKS 16
#define FB 64                     // fine bins per bucket = 8^3 superregions
#define NSUP 4096                 // total superregions
#define PPT 16
#define K3_BLOCK 256
#define PPB (K3_BLOCK * PPT)      // 4096 points per block
#define CMAX 2560                 // max chunk size staged in fineC (40KB LDS)

__device__ __forceinline__ uint32_t bucket_of(float px, float py, float pz) {
    uint32_t bx = ((uint32_t)(int)floorf(px * 128.0f)) >> 5;
    uint32_t by = ((uint32_t)(int)floorf(py * 128.0f)) >> 5;
    uint32_t bz = ((uint32_t)(int)floorf(pz * 128.0f)) >> 5;
    return (bx << 4) | (by << 2) | bz;
}

// fine bin within bucket: superregion coord (cell>>3)&3 per axis
__device__ __forceinline__ uint32_t fine_of(float px, float py, float pz) {
    uint32_t fx = (((uint32_t)(int)floorf(px * 128.0f)) >> 3) & 3u;
    uint32_t fy = (((uint32_t)(int)floorf(py * 128.0f)) >> 3) & 3u;
    uint32_t fz = (((uint32_t)(int)floorf(pz * 128.0f)) >> 3) & 3u;
    return (fx << 4) | (fy << 2) | fz;
}

__device__ __forceinline__ float4 interp_point(float px, float py, float pz,
                                               const float* __restrict__ table) {
    int lx = (int)floorf(px * 128.0f);
    int ly = (int)floorf(py * 128.0f);
    int lz = (int)floorf(pz * 128.0f);
    const float inv = 1.0f / 128.0f;
    float w0x = (px - (float)lx * inv) * 128.0f;
    float w1x = ((float)(lx + 1) * inv - px) * 128.0f;
    float w0y = (py - (float)ly * inv) * 128.0f;
    float w1y = ((float)(ly + 1) * inv - py) * 128.0f;
    float w0z = (pz - (float)lz * inv) * 128.0f;
    float w1z = ((float)(lz + 1) * inv - pz) * 128.0f;
    uint32_t hx0 = (uint32_t)lx, hx1 = (uint32_t)(lx + 1);
    uint32_t hy0 = (uint32_t)ly * P1, hy1 = (uint32_t)(ly + 1) * P1;
    uint32_t hz0 = (uint32_t)lz * P2, hz1 = (uint32_t)(lz + 1) * P2;
    float acc0 = 0.f, acc1 = 0.f, acc2 = 0.f, acc3 = 0.f;
#pragma unroll
    for (int c = 0; c < 8; ++c) {
        int bx = (c >> 2) & 1, by = (c >> 1) & 1, bz = c & 1;
        uint32_t h = ((bx ? hx1 : hx0) ^ (by ? hy1 : hy0) ^ (bz ? hz1 : hz0)) & HASH_MASK;
        const float4 v = *reinterpret_cast<const float4*>(table + (size_t)h * 4);
        float w = ((bx ? w1x : w0x) * (by ? w1y : w0y)) * (bz ? w1z : w0z);
        acc0 += v.x * w; acc1 += v.y * w; acc2 += v.z * w; acc3 += v.w * w;
    }
    return make_float4(acc0, acc1, acc2, acc3);
}

// ---- K1: per-block LDS histogram (64 bins) ----
__global__ __launch_bounds__(K3_BLOCK) void hist_kernel(
    const float* __restrict__ pos, uint32_t* __restrict__ hist, int batch)
{
    __shared__ uint32_t h[NBUCK];
    int tid = threadIdx.x;
    size_t start = (size_t)blockIdx.x * PPB;
    if (tid < NBUCK) h[tid] = 0;
    __syncthreads();
#pragma unroll
    for (int k = 0; k < PPT; ++k) {
        size_t i = start + (size_t)k * K3_BLOCK + tid;
        if (i < (size_t)batch) {
            float px = pos[3 * i + 0];
            float py = pos[3 * i + 1];
            float pz = pos[3 * i + 2];
            atomicAdd(&h[bucket_of(px, py, pz)], 1u);
        }
    }
    __syncthreads();
    if (tid < NBUCK && h[tid]) atomicAdd(&hist[tid], h[tid]);
}

// ---- K2: 64-bin exclusive scan ----
__global__ __launch_bounds__(64) void scan_kernel(
    const uint32_t* __restrict__ hist, uint32_t* __restrict__ cursor)
{
    int t = threadIdx.x;
    uint32_t v = hist[t];
    uint32_t inc = v;
    for (int off = 1; off < 64; off <<= 1) {
        uint32_t n = __shfl_up(inc, off);
        if (t >= off) inc += n;
    }
    cursor[t] = inc - v;
}

// ---- K3: LDS-staged coarse scatter (coalesced) ----
// After this kernel cursor[b] == inclusive end offset of bucket b.
__global__ __launch_bounds__(K3_BLOCK) void scatter_kernel(
    const float* __restrict__ pos, uint32_t* __restrict__ cursor,
    float4* __restrict__ sorted, int batch)
{
    __shared__ float4 staged[PPB];
    __shared__ uint32_t h[NBUCK], lbase[NBUCK], gbase[NBUCK], lcur[NBUCK];
    int tid = threadIdx.x;
    size_t start = (size_t)blockIdx.x * PPB;

    if (tid < NBUCK) h[tid] = 0;
    __syncthreads();

    float px[PPT], py[PPT], pz[PPT];
    uint32_t bb[PPT];
#pragma unroll
    for (int k = 0; k < PPT; ++k) {
        size_t i = start + (size_t)k * K3_BLOCK + tid;
        px[k] = pos[3 * i + 0];
        py[k] = pos[3 * i + 1];
        pz[k] = pos[3 * i + 2];
        bb[k] = bucket_of(px[k], py[k], pz[k]);
        atomicAdd(&h[bb[k]], 1u);
    }
    __syncthreads();

    if (tid < NBUCK) {
        uint32_t v = h[tid];
        uint32_t inc = v;
        for (int off = 1; off < 64; off <<= 1) {
            uint32_t n = __shfl_up(inc, off);
            if (tid >= off) inc += n;
        }
        uint32_t excl = inc - v;
        lbase[tid] = excl;
        lcur[tid] = excl;
        gbase[tid] = atomicAdd(&cursor[tid], v);
    }
    __syncthreads();

#pragma unroll
    for (int k = 0; k < PPT; ++k) {
        size_t i = start + (size_t)k * K3_BLOCK + tid;
        uint32_t slot = atomicAdd(&lcur[bb[k]], 1u);
        staged[slot] = make_float4(px[k], py[k], pz[k], __uint_as_float((uint32_t)i));
    }
    __syncthreads();

#pragma unroll
    for (int k = 0; k < PPT; ++k) {
        int j = k * K3_BLOCK + tid;
        float4 s = staged[j];
        uint32_t b = bucket_of(s.x, s.y, s.z);
        sorted[gbase[b] + ((uint32_t)j - lbase[b])] = s;
    }
}

// ---- fineA: per (bucket,chunk) 64-bin histogram ----
__global__ __launch_bounds__(256) void fineA_kernel(
    const float4* __restrict__ sorted, const uint32_t* __restrict__ cursor,
    uint32_t* __restrict__ chist)
{
    __shared__ uint32_t h[FB];
    int tid = threadIdx.x;
    int b = blockIdx.x >> 4, c = blockIdx.x & (CHUNKS - 1);
    uint32_t bs = b ? cursor[b - 1] : 0u;
    uint32_t be = cursor[b];
    uint32_t n = be - bs;
    uint32_t csz = (n + CHUNKS - 1) / CHUNKS;
    uint32_t cs = bs + (uint32_t)c * csz;
    uint32_t ce = min(cs + csz, be);

    if (tid < FB) h[tid] = 0;
    __syncthreads();
    for (uint32_t j = cs + tid; j < ce; j += 256) {
        float4 s = sorted[j];
        atomicAdd(&h[fine_of(s.x, s.y, s.z)], 1u);
    }
    __syncthreads();
    if (tid < FB) chist[((uint32_t)blockIdx.x << 6) + tid] = h[tid];
}

// ---- fineB: per-bucket bases; one wave per bucket ----
// chist[(b*CHUNKS+c)*64+f] -> overwritten with global base for that run.
// Also writes sstart[b*64+f] = global start of superregion.
__global__ __launch_bounds__(64) void fineB_kernel(
    uint32_t* __restrict__ chist, const uint32_t* __restrict__ cursor,
    uint32_t* __restrict__ sstart)
{
    int b = blockIdx.x;
    int f = threadIdx.x;
    uint32_t bs = b ? cursor[b - 1] : 0u;

    uint32_t cnt[CHUNKS];
    uint32_t tot = 0;
#pragma unroll
    for (int c = 0; c < CHUNKS; ++c) {
        cnt[c] = chist[(((uint32_t)b * CHUNKS + c) << 6) + f];
        tot += cnt[c];
    }
    // exclusive scan of tot over the 64 fine bins (single wave)
    uint32_t inc = tot;
    for (int off = 1; off < 64; off <<= 1) {
        uint32_t n = __shfl_up(inc, off);
        if (f >= off) inc += n;
    }
    uint32_t fbase = bs + inc - tot;
    sstart[((uint32_t)b << 6) + f] = fbase;
    uint32_t run = fbase;
#pragma unroll
    for (int c = 0; c < CHUNKS; ++c) {
        chist[(((uint32_t)b * CHUNKS + c) << 6) + f] = run;
        run += cnt[c];
    }
}

// ---- fineC: LDS-staged coalesced scatter into superregion order ----
__global__ __launch_bounds__(256) void fineC_kernel(
    const float4* __restrict__ sorted, const uint32_t* __restrict__ cursor,
    const uint32_t* __restrict__ cbase, float4* __restrict__ sorted2)
{
    __shared__ float4 staged[CMAX];         // 40 KB
    __shared__ uint32_t h[FB], lbase[FB], lcur[FB], gb[FB];
    int tid = threadIdx.x;
    int b = blockIdx.x >> 4, c = blockIdx.x & (CHUNKS - 1);
    uint32_t bs = b ? cursor[b - 1] : 0u;
    uint32_t be = cursor[b];
    uint32_t n = be - bs;
    uint32_t csz = (n + CHUNKS - 1) / CHUNKS;
    uint32_t cs = bs + (uint32_t)c * csz;
    uint32_t ce = min(cs + csz, be);
    if (ce <= cs) return;
    uint32_t m = ce - cs;

    if (tid < FB) h[tid] = 0;
    __syncthreads();

    for (uint32_t j = cs + tid; j < ce; j += 256)  {
        float4 s = sorted[j];
        atomicAdd(&h[fine_of(s.x, s.y, s.z)], 1u);
    }
    __syncthreads();

    if (tid < FB) {
        uint32_t v = h[tid];
        uint32_t inc = v;
        for (int off = 1; off < 64; off <<= 1) {
            uint32_t nn = __shfl_up(inc, off);
            if (tid >= off) inc += nn;
        }
        lbase[tid] = inc - v;
        lcur[tid] = inc - v;
        gb[tid] = cbase[(((uint32_t)b * CHUNKS + c) << 6) + tid];
    }
    __syncthreads();

    for (uint32_t j = cs + tid; j < ce; j += 256) {
        float4 s = sorted[j];
        uint32_t slot = atomicAdd(&lcur[fine_of(s.x, s.y, s.z)], 1u);
        staged[slot] = s;
    }
    __syncthreads();

    // coalesced: consecutive staged slots of a fine run -> consecutive global
    for (uint32_t j = tid; j < m; j += 256) {
        float4 s = staged[j];
        uint32_t f = fine_of(s.x, s.y, s.z);
        sorted2[gb[f] + (j - lbase[f])] = s;
    }
}

// ---- K4: block-per-superregion, 729 LDS corners, scatter to out[orig] ----
__global__ __launch_bounds__(256) void interp_super_kernel(
    const float4* __restrict__ sorted2, const uint32_t* __restrict__ sstart,
    const float* __restrict__ table, float4* __restrict__ out4, int batch)
{
    __shared__ float4 corners[729];          // 11.7 KB, block-shared
    int bid = blockIdx.x;
    int swz = (bid & 7) * (NSUP >> 3) + (bid >> 3);   // XCD-chunked
    int tid = threadIdx.x;
    uint32_t r = (uint32_t)swz;
    uint32_t start = sstart[r];
    uint32_t end = (r == NSUP - 1) ? (uint32_t)batch : sstart[r + 1];
    if (start >= end) return;                 // uniform: no thread reaches sync

    float4 s0 = sorted2[start];
    int rbx = (((int)floorf(s0.x * 128.0f)) >> 3) << 3;
    int rby = (((int)floorf(s0.y * 128.0f)) >> 3) << 3;
    int rbz = (((int)floorf(s0.z * 128.0f)) >> 3) << 3;

    for (int idx = tid; idx < 729; idx += 256) {
        int ci = idx / 81;
        int rem = idx - ci * 81;
        int cj = rem / 9;
        int ck = rem - cj * 9;
        uint32_t h = ((uint32_t)(rbx + ci) ^
                      (uint32_t)(rby + cj) * P1 ^
                      (uint32_t)(rbz + ck) * P2) & HASH_MASK;
        corners[idx] = *reinterpret_cast<const float4*>(table + (size_t)h * 4);
    }
    __syncthreads();

    const float inv = 1.0f / 128.0f;
    for (uint32_t p = start + tid; p < end; p += 256) {
        float4 s = sorted2[p];
        float px = s.x, py = s.y, pz = s.z;
        int lx = (int)floorf(px * 128.0f);
        int ly = (int)floorf(py * 128.0f);
        int lz = (int)floorf(pz * 128.0f);
        float w0x = (px - (float)lx * inv) * 128.0f;
        float w1x = ((float)(lx + 1) * inv - px) * 128.0f;
        float w0y = (py - (float)ly * inv) * 128.0f;
        float w1y = ((float)(ly + 1) * inv - py) * 128.0f;
        float w0z = (pz - (float)lz * inv) * 128.0f;
        float w1z = ((float)(lz + 1) * inv - pz) * 128.0f;
        int li = lx - rbx, lj = ly - rby, lk = lz - rbz;   // in [0,7]
        int base = li * 81 + lj * 9 + lk;

        float acc0 = 0.f, acc1 = 0.f, acc2 = 0.f, acc3 = 0.f;
#pragma unroll
        for (int c = 0; c < 8; ++c) {
            int bx = (c >> 2) & 1, by = (c >> 1) & 1, bz = c & 1;
            float4 v = corners[base + bx * 81 + by * 9 + bz];
            float w = ((bx ? w1x : w0x) * (by ? w1y : w0y)) * (bz ? w1z : w0z);
            acc0 += v.x * w; acc1 += v.y * w; acc2 += v.z * w; acc3 += v.w * w;
        }
        out4[__float_as_uint(s.w)] = make_float4(acc0, acc1, acc2, acc3);
    }
}

// ---- fallback paths ----
__global__ __launch_bounds__(256) void interp_scatter_kernel(
    const float4* __restrict__ sorted, const float* __restrict__ table,
    float4* __restrict__ out4, int batch, int nwg)
{
    int bid = blockIdx.x;
    int q = nwg >> 3;
    int swz = (bid & 7) * q + (bid >> 3);
    int i = swz * 256 + threadIdx.x;
    if (i >= batch) return;
    float4 s = sorted[i];
    float4 r = interp_point(s.x, s.y, s.z, table);
    out4[__float_as_uint(s.w)] = r;
}

__global__ __launch_bounds__(256) void interp_direct_kernel(
    const float* __restrict__ pos, const float* __restrict__ table,
    float4* __restrict__ out4, int batch)
{
    int i = blockIdx.x * 256 + threadIdx.x;
    if (i >= batch) return;
    out4[i] = interp_point(pos[3 * (size_t)i], pos[3 * (size_t)i + 1],
                           pos[3 * (size_t)i + 2], table);
}

extern "C" void kernel_launch(void* const* d_in, const int* in_sizes, int n_in,
                              void* d_out, int out_size, void* d_ws, size_t ws_size,
                              hipStream_t stream) {
    const float* pos   = (const float*)d_in[0];   // (2^21, 3)
    const float* table = (const float*)d_in[1];   // (2^22, 4)
    float4* out4 = (float4*)d_out;                // (2^21, 4)

    int batch = in_sizes[0] / 3;                  // 2^21
    int blocks256 = (batch + 255) / 256;          // 8192

    size_t sorted_off  = 512;
    size_t sorted2_off = sorted_off + (size_t)batch * 16;
    size_t chist_off   = sorted2_off + (size_t)batch * 16;
    size_t chist_bytes = (size_t)NBUCK * CHUNKS * FB * 4;     // 256 KB
    size_t sstart_off  = chist_off + chist_bytes;
    size_t need_min  = sorted_off + (size_t)batch * 16;
    size_t need_full = sstart_off + (size_t)NSUP * 4;

    bool exact = (batch % PPB == 0) && ((blocks256 & 7) == 0);
    if (ws_size < need_min || !exact) {
        interp_direct_kernel<<<blocks256, 256, 0, stream>>>(pos, table, out4, batch);
        return;
    }

    uint32_t* hist    = (uint32_t*)d_ws;
    uint32_t* cursor  = (uint32_t*)((char*)d_ws + 256);
    float4*   sorted  = (float4*)((char*)d_ws + sorted_off);
    float4*   sorted2 = (float4*)((char*)d_ws + sorted2_off);
    uint32_t* chist   = (uint32_t*)((char*)d_ws + chist_off);
    uint32_t* sstart  = (uint32_t*)((char*)d_ws + sstart_off);

    int sblocks = batch / PPB;                    // 512

    hipMemsetAsync(hist, 0, NBUCK * sizeof(uint32_t), stream);
    hist_kernel<<<sblocks, K3_BLOCK, 0, stream>>>(pos, hist, batch);
    scan_kernel<<<1, 64, 0, stream>>>(hist, cursor);
    scatter_kernel<<<sblocks, K3_BLOCK, 0, stream>>>(pos, cursor, sorted, batch);

    if (ws_size >= need_full) {
        fineA_kernel<<<NBUCK * CHUNKS, 256, 0, stream>>>(sorted, cursor, chist);
        fineB_kernel<<<NBUCK, 64, 0, stream>>>(chist, cursor, sstart);
        fineC_kernel<<<NBUCK * CHUNKS, 256, 0, stream>>>(sorted, cursor, chist, sorted2);
        interp_super_kernel<<<NSUP, 256, 0, stream>>>(sorted2, sstart, table, out4, batch);
    } else {
        interp_scatter_kernel<<<blocks256, 256, 0, stream>>>(sorted, table, out4,
                                                             batch, blocks256);
    }
}

// Round 10
// 106.883 us; speedup vs baseline: 1.3217x; 1.0374x over previous
//
#include <hip/hip_runtime.h>
#include <stdint.h>

// HashedInterpolator R9: R8 structure + key-byte reuse in the fine sort.
// K3 emits key[slot] = fine bin (1B/point). fineA histograms from key (2MB
// instead of 32MB); fineB preserves counts (chist) and writes run bases to
// cbase; fineC drops its histogram pass (wave-scan of chist counts).
// K4 (block-per-superregion, 729 LDS corners) unchanged.

#define HASH_MASK 0x3FFFFFu
#define P1 19349663u
#define P2 83492791u
#define NBUCK 64
#define CHUNKS 16
#define FB 64                     // fine bins per bucket = 8^3 superregions
#define NSUP 4096                 // total superregions
#define PPT 16
#define K3_BLOCK 256
#define PPB (K3_BLOCK * PPT)      // 4096 points per block
#define CMAX 2560                 // max chunk size staged in fineC (40KB LDS)

__device__ __forceinline__ uint32_t bucket_of(float px, float py, float pz) {
    uint32_t bx = ((uint32_t)(int)floorf(px * 128.0f)) >> 5;
    uint32_t by = ((uint32_t)(int)floorf(py * 128.0f)) >> 5;
    uint32_t bz = ((uint32_t)(int)floorf(pz * 128.0f)) >> 5;
    return (bx << 4) | (by << 2) | bz;
}

// fine bin within bucket: superregion coord (cell>>3)&3 per axis
__device__ __forceinline__ uint32_t fine_of(float px, float py, float pz) {
    uint32_t fx = (((uint32_t)(int)floorf(px * 128.0f)) >> 3) & 3u;
    uint32_t fy = (((uint32_t)(int)floorf(py * 128.0f)) >> 3) & 3u;
    uint32_t fz = (((uint32_t)(int)floorf(pz * 128.0f)) >> 3) & 3u;
    return (fx << 4) | (fy << 2) | fz;
}

__device__ __forceinline__ float4 interp_point(float px, float py, float pz,
                                               const float* __restrict__ table) {
    int lx = (int)floorf(px * 128.0f);
    int ly = (int)floorf(py * 128.0f);
    int lz = (int)floorf(pz * 128.0f);
    const float inv = 1.0f / 128.0f;
    float w0x = (px - (float)lx * inv) * 128.0f;
    float w1x = ((float)(lx + 1) * inv - px) * 128.0f;
    float w0y = (py - (float)ly * inv) * 128.0f;
    float w1y = ((float)(ly + 1) * inv - py) * 128.0f;
    float w0z = (pz - (float)lz * inv) * 128.0f;
    float w1z = ((float)(lz + 1) * inv - pz) * 128.0f;
    uint32_t hx0 = (uint32_t)lx, hx1 = (uint32_t)(lx + 1);
    uint32_t hy0 = (uint32_t)ly * P1, hy1 = (uint32_t)(ly + 1) * P1;
    uint32_t hz0 = (uint32_t)lz * P2, hz1 = (uint32_t)(lz + 1) * P2;
    float acc0 = 0.f, acc1 = 0.f, acc2 = 0.f, acc3 = 0.f;
#pragma unroll
    for (int c = 0; c < 8; ++c) {
        int bx = (c >> 2) & 1, by = (c >> 1) & 1, bz = c & 1;
        uint32_t h = ((bx ? hx1 : hx0) ^ (by ? hy1 : hy0) ^ (bz ? hz1 : hz0)) & HASH_MASK;
        const float4 v = *reinterpret_cast<const float4*>(table + (size_t)h * 4);
        float w = ((bx ? w1x : w0x) * (by ? w1y : w0y)) * (bz ? w1z : w0z);
        acc0 += v.x * w; acc1 += v.y * w; acc2 += v.z * w; acc3 += v.w * w;
    }
    return make_float4(acc0, acc1, acc2, acc3);
}

// ---- K1: per-block LDS histogram (64 bins) ----
__global__ __launch_bounds__(K3_BLOCK) void hist_kernel(
    const float* __restrict__ pos, uint32_t* __restrict__ hist, int batch)
{
    __shared__ uint32_t h[NBUCK];
    int tid = threadIdx.x;
    size_t start = (size_t)blockIdx.x * PPB;
    if (tid < NBUCK) h[tid] = 0;
    __syncthreads();
#pragma unroll
    for (int k = 0; k < PPT; ++k) {
        size_t i = start + (size_t)k * K3_BLOCK + tid;
        if (i < (size_t)batch) {
            float px = pos[3 * i + 0];
            float py = pos[3 * i + 1];
            float pz = pos[3 * i + 2];
            atomicAdd(&h[bucket_of(px, py, pz)], 1u);
        }
    }
    __syncthreads();
    if (tid < NBUCK && h[tid]) atomicAdd(&hist[tid], h[tid]);
}

// ---- K2: 64-bin exclusive scan ----
__global__ __launch_bounds__(64) void scan_kernel(
    const uint32_t* __restrict__ hist, uint32_t* __restrict__ cursor)
{
    int t = threadIdx.x;
    uint32_t v = hist[t];
    uint32_t inc = v;
    for (int off = 1; off < 64; off <<= 1) {
        uint32_t n = __shfl_up(inc, off);
        if (t >= off) inc += n;
    }
    cursor[t] = inc - v;
}

// ---- K3: LDS-staged coarse scatter (coalesced) + key emission ----
// After this kernel cursor[b] == inclusive end offset of bucket b.
__global__ __launch_bounds__(K3_BLOCK) void scatter_kernel(
    const float* __restrict__ pos, uint32_t* __restrict__ cursor,
    float4* __restrict__ sorted, uint8_t* __restrict__ key, int batch)
{
    __shared__ float4 staged[PPB];
    __shared__ uint32_t h[NBUCK], lbase[NBUCK], gbase[NBUCK], lcur[NBUCK];
    int tid = threadIdx.x;
    size_t start = (size_t)blockIdx.x * PPB;

    if (tid < NBUCK) h[tid] = 0;
    __syncthreads();

    float px[PPT], py[PPT], pz[PPT];
    uint32_t bb[PPT];
#pragma unroll
    for (int k = 0; k < PPT; ++k) {
        size_t i = start + (size_t)k * K3_BLOCK + tid;
        px[k] = pos[3 * i + 0];
        py[k] = pos[3 * i + 1];
        pz[k] = pos[3 * i + 2];
        bb[k] = bucket_of(px[k], py[k], pz[k]);
        atomicAdd(&h[bb[k]], 1u);
    }
    __syncthreads();

    if (tid < NBUCK) {
        uint32_t v = h[tid];
        uint32_t inc = v;
        for (int off = 1; off < 64; off <<= 1) {
            uint32_t n = __shfl_up(inc, off);
            if (tid >= off) inc += n;
        }
        uint32_t excl = inc - v;
        lbase[tid] = excl;
        lcur[tid] = excl;
        gbase[tid] = atomicAdd(&cursor[tid], v);
    }
    __syncthreads();

#pragma unroll
    for (int k = 0; k < PPT; ++k) {
        size_t i = start + (size_t)k * K3_BLOCK + tid;
        uint32_t slot = atomicAdd(&lcur[bb[k]], 1u);
        staged[slot] = make_float4(px[k], py[k], pz[k], __uint_as_float((uint32_t)i));
    }
    __syncthreads();

#pragma unroll
    for (int k = 0; k < PPT; ++k) {
        int j = k * K3_BLOCK + tid;
        float4 s = staged[j];
        uint32_t b = bucket_of(s.x, s.y, s.z);
        uint32_t slot = gbase[b] + ((uint32_t)j - lbase[b]);
        sorted[slot] = s;
        key[slot] = (uint8_t)fine_of(s.x, s.y, s.z);
    }
}

// ---- fineA: per (bucket,chunk) 64-bin histogram from key bytes ----
__global__ __launch_bounds__(256) void fineA_kernel(
    const uint8_t* __restrict__ key, const uint32_t* __restrict__ cursor,
    uint32_t* __restrict__ chist)
{
    __shared__ uint32_t h[FB];
    int tid = threadIdx.x;
    int b = blockIdx.x >> 4, c = blockIdx.x & (CHUNKS - 1);
    uint32_t bs = b ? cursor[b - 1] : 0u;
    uint32_t be = cursor[b];
    uint32_t n = be - bs;
    uint32_t csz = (n + CHUNKS - 1) / CHUNKS;
    uint32_t cs = bs + (uint32_t)c * csz;
    uint32_t ce = min(cs + csz, be);

    if (tid < FB) h[tid] = 0;
    __syncthreads();
    for (uint32_t j = cs + tid; j < ce; j += 256)
        atomicAdd(&h[key[j]], 1u);
    __syncthreads();
    if (tid < FB) chist[((uint32_t)blockIdx.x << 6) + tid] = h[tid];
}

// ---- fineB: per-bucket bases; counts preserved in chist ----
__global__ __launch_bounds__(64) void fineB_kernel(
    const uint32_t* __restrict__ chist, const uint32_t* __restrict__ cursor,
    uint32_t* __restrict__ cbase, uint32_t* __restrict__ sstart)
{
    int b = blockIdx.x;
    int f = threadIdx.x;
    uint32_t bs = b ? cursor[b - 1] : 0u;

    uint32_t cnt[CHUNKS];
    uint32_t tot = 0;
#pragma unroll
    for (int c = 0; c < CHUNKS; ++c) {
        cnt[c] = chist[(((uint32_t)b * CHUNKS + c) << 6) + f];
        tot += cnt[c];
    }
    uint32_t inc = tot;
    for (int off = 1; off < 64; off <<= 1) {
        uint32_t n = __shfl_up(inc, off);
        if (f >= off) inc += n;
    }
    uint32_t fbase = bs + inc - tot;
    sstart[((uint32_t)b << 6) + f] = fbase;
    uint32_t run = fbase;
#pragma unroll
    for (int c = 0; c < CHUNKS; ++c) {
        cbase[(((uint32_t)b * CHUNKS + c) << 6) + f] = run;
        run += cnt[c];
    }
}

// ---- fineC: stage by key, coalesced scatter; no histogram pass ----
__global__ __launch_bounds__(256) void fineC_kernel(
    const float4* __restrict__ sorted, const uint8_t* __restrict__ key,
    const uint32_t* __restrict__ cursor, const uint32_t* __restrict__ chist,
    const uint32_t* __restrict__ cbase, float4* __restrict__ sorted2)
{
    __shared__ float4 staged[CMAX];         // 40 KB
    __shared__ uint32_t lbase[FB], lcur[FB], gb[FB];
    int tid = threadIdx.x;
    int b = blockIdx.x >> 4, c = blockIdx.x & (CHUNKS - 1);
    uint32_t bs = b ? cursor[b - 1] : 0u;
    uint32_t be = cursor[b];
    uint32_t n = be - bs;
    uint32_t csz = (n + CHUNKS - 1) / CHUNKS;
    uint32_t cs = bs + (uint32_t)c * csz;
    uint32_t ce = min(cs + csz, be);
    if (ce <= cs) return;
    uint32_t m = ce - cs;

    if (tid < FB) {
        uint32_t v = chist[(((uint32_t)b * CHUNKS + c) << 6) + tid];
        uint32_t inc = v;
        for (int off = 1; off < 64; off <<= 1) {
            uint32_t nn = __shfl_up(inc, off);
            if (tid >= off) inc += nn;
        }
        lbase[tid] = inc - v;
        lcur[tid] = inc - v;
        gb[tid] = cbase[(((uint32_t)b * CHUNKS + c) << 6) + tid];
    }
    __syncthreads();

    for (uint32_t j = cs + tid; j < ce; j += 256) {
        float4 s = sorted[j];
        uint32_t slot = atomicAdd(&lcur[key[j]], 1u);
        staged[slot] = s;
    }
    __syncthreads();

    // coalesced: consecutive staged slots of a fine run -> consecutive global
    for (uint32_t j = tid; j < m; j += 256) {
        float4 s = staged[j];
        uint32_t f = fine_of(s.x, s.y, s.z);
        sorted2[gb[f] + (j - lbase[f])] = s;
    }
}

// ---- K4: block-per-superregion, 729 LDS corners, scatter to out[orig] ----
__global__ __launch_bounds__(256) void interp_super_kernel(
    const float4* __restrict__ sorted2, const uint32_t* __restrict__ sstart,
    const float* __restrict__ table, float4* __restrict__ out4, int batch)
{
    __shared__ float4 corners[729];          // 11.7 KB, block-shared
    int bid = blockIdx.x;
    int swz = (bid & 7) * (NSUP >> 3) + (bid >> 3);   // XCD-chunked
    int tid = threadIdx.x;
    uint32_t r = (uint32_t)swz;
    uint32_t start = sstart[r];
    uint32_t end = (r == NSUP - 1) ? (uint32_t)batch : sstart[r + 1];
    if (start >= end) return;                 // uniform: no thread reaches sync

    float4 s0 = sorted2[start];
    int rbx = (((int)floorf(s0.x * 128.0f)) >> 3) << 3;
    int rby = (((int)floorf(s0.y * 128.0f)) >> 3) << 3;
    int rbz = (((int)floorf(s0.z * 128.0f)) >> 3) << 3;

    for (int idx = tid; idx < 729; idx += 256) {
        int ci = idx / 81;
        int rem = idx - ci * 81;
        int cj = rem / 9;
        int ck = rem - cj * 9;
        uint32_t h = ((uint32_t)(rbx + ci) ^
                      (uint32_t)(rby + cj) * P1 ^
                      (uint32_t)(rbz + ck) * P2) & HASH_MASK;
        corners[idx] = *reinterpret_cast<const float4*>(table + (size_t)h * 4);
    }
    __syncthreads();

    const float inv = 1.0f / 128.0f;
    for (uint32_t p = start + tid; p < end; p += 256) {
        float4 s = sorted2[p];
        float px = s.x, py = s.y, pz = s.z;
        int lx = (int)floorf(px * 128.0f);
        int ly = (int)floorf(py * 128.0f);
        int lz = (int)floorf(pz * 128.0f);
        float w0x = (px - (float)lx * inv) * 128.0f;
        float w1x = ((float)(lx + 1) * inv - px) * 128.0f;
        float w0y = (py - (float)ly * inv) * 128.0f;
        float w1y = ((float)(ly + 1) * inv - py) * 128.0f;
        float w0z = (pz - (float)lz * inv) * 128.0f;
        float w1z = ((float)(lz + 1) * inv - pz) * 128.0f;
        int li = lx - rbx, lj = ly - rby, lk = lz - rbz;   // in [0,7]
        int base = li * 81 + lj * 9 + lk;

        float acc0 = 0.f, acc1 = 0.f, acc2 = 0.f, acc3 = 0.f;
#pragma unroll
        for (int c = 0; c < 8; ++c) {
            int bx = (c >> 2) & 1, by = (c >> 1) & 1, bz = c & 1;
            float4 v = corners[base + bx * 81 + by * 9 + bz];
            float w = ((bx ? w1x : w0x) * (by ? w1y : w0y)) * (bz ? w1z : w0z);
            acc0 += v.x * w; acc1 += v.y * w; acc2 += v.z * w; acc3 += v.w * w;
        }
        out4[__float_as_uint(s.w)] = make_float4(acc0, acc1, acc2, acc3);
    }
}

// ---- fallback paths ----
__global__ __launch_bounds__(256) void interp_direct_kernel(
    const float* __restrict__ pos, const float* __restrict__ table,
    float4* __restrict__ out4, int batch)
{
    int i = blockIdx.x * 256 + threadIdx.x;
    if (i >= batch) return;
    out4[i] = interp_point(pos[3 * (size_t)i], pos[3 * (size_t)i + 1],
                           pos[3 * (size_t)i + 2], table);
}

extern "C" void kernel_launch(void* const* d_in, const int* in_sizes, int n_in,
                              void* d_out, int out_size, void* d_ws, size_t ws_size,
                              hipStream_t stream) {
    const float* pos   = (const float*)d_in[0];   // (2^21, 3)
    const float* table = (const float*)d_in[1];   // (2^22, 4)
    float4* out4 = (float4*)d_out;                // (2^21, 4)

    int batch = in_sizes[0] / 3;                  // 2^21
    int blocks256 = (batch + 255) / 256;          // 8192

    size_t sorted_off  = 512;
    size_t sorted2_off = sorted_off + (size_t)batch * 16;
    size_t chist_off   = sorted2_off + (size_t)batch * 16;
    size_t chist_bytes = (size_t)NBUCK * CHUNKS * FB * 4;     // 256 KB
    size_t cbase_off   = chist_off + chist_bytes;
    size_t sstart_off  = cbase_off + chist_bytes;
    size_t key_off     = sstart_off + (size_t)NSUP * 4;
    size_t need_full   = key_off + (size_t)batch;

    bool exact = (batch % PPB == 0) && ((blocks256 & 7) == 0);
    if (ws_size < need_full || !exact) {
        interp_direct_kernel<<<blocks256, 256, 0, stream>>>(pos, table, out4, batch);
        return;
    }

    uint32_t* hist    = (uint32_t*)d_ws;
    uint32_t* cursor  = (uint32_t*)((char*)d_ws + 256);
    float4*   sorted  = (float4*)((char*)d_ws + sorted_off);
    float4*   sorted2 = (float4*)((char*)d_ws + sorted2_off);
    uint32_t* chist   = (uint32_t*)((char*)d_ws + chist_off);
    uint32_t* cbase   = (uint32_t*)((char*)d_ws + cbase_off);
    uint32_t* sstart  = (uint32_t*)((char*)d_ws + sstart_off);
    uint8_t*  key     = (uint8_t*)((char*)d_ws + key_off);

    int sblocks = batch / PPB;                    // 512

    hipMemsetAsync(hist, 0, NBUCK * sizeof(uint32_t), stream);
    hist_kernel<<<sblocks, K3_BLOCK, 0, stream>>>(pos, hist, batch);
    scan_kernel<<<1, 64, 0, stream>>>(hist, cursor);
    scatter_kernel<<<sblocks, K3_BLOCK, 0, stream>>>(pos, cursor, sorted, key, batch);
    fineA_kernel<<<NBUCK * CHUNKS, 256, 0, stream>>>(key, cursor, chist);
    fineB_kernel<<<NBUCK, 64, 0, stream>>>(chist, cursor, cbase, sstart);
    fineC_kernel<<<NBUCK * CHUNKS, 256, 0, stream>>>(sorted, key, cursor, chist,
                                                     cbase, sorted2);
    interp_super_kernel<<<NSUP, 256, 0, stream>>>(sorted2, sstart, table, out4, batch);
}